// Round 5
// baseline (33.616 us; speedup 1.0000x reference)
//
#include <hip/hip_runtime.h>
#include <stdint.h>

#define B_DIM 64
#define L_DIM 4096
#define D_DIM 256
#define TGT 256
#define BLK 256                      // threads per block (4 waves)
#define ROWS_PER_BLOCK 8
#define NG (TGT / ROWS_PER_BLOCK)    // 32 groups per batch

typedef float f32x4 __attribute__((ext_vector_type(4)));

__device__ __forceinline__ int idx_of(int k, float nf) {
    // matches jnp: minimum(round(k/256 * n), n-1) with round-half-even
    float x = rintf((float)k * (1.0f / 256.0f) * nf);
    x = fminf(x, nf - 1.0f);
    return (int)x;
}

__global__ __launch_bounds__(BLK)
void AggregateVideo_kernel(const uint8_t* __restrict__ mask_raw,
                           const float* __restrict__ feats,
                           float* __restrict__ out) {
    __shared__ unsigned short pos[L_DIM];           // compact idx -> original row
    __shared__ unsigned long long words[L_DIM / 64];
    __shared__ int pref[L_DIM / 64];
    __shared__ int flags[2];
    __shared__ int nsh;

    const int tid  = threadIdx.x;
    const int b    = blockIdx.y;
    const int g    = blockIdx.x;
    const int wv   = tid >> 6;
    const int lane = tid & 63;

    // ---- mask dtype detection on first 4096 bytes (valid under all layouts)
    if (tid == 0) { flags[0] = 1; flags[1] = 1; }
    __syncthreads();
    {
        const uint32_t* mw = (const uint32_t*)mask_raw;
        bool bad_int = false, bad_f32 = false;
        #pragma unroll
        for (int i = 0; i < 4; ++i) {
            uint32_t w = mw[tid + BLK * i];
            if (w > 1u) bad_int = true;
            if (w != 0u && w != 0x3F800000u) bad_f32 = true;
        }
        if (bad_int) flags[0] = 0;
        if (bad_f32) flags[1] = 0;
    }
    __syncthreads();
    const int flag = flags[0] ? 1 : (flags[1] ? 2 : 0); // 1=int32, 2=f32, 0=byte

    // ---- ballot-compaction: coalesced mask loads -> 64 bitmask words
    {
        if (flag == 1) {
            const int32_t* m = (const int32_t*)mask_raw + (size_t)b * L_DIM;
            #pragma unroll
            for (int i = 0; i < L_DIM / BLK; ++i) {
                const int j = i * BLK + tid;
                unsigned long long bal = __ballot(m[j] != 0);
                if (lane == 0) words[j >> 6] = bal;
            }
        } else if (flag == 2) {
            const float* m = (const float*)mask_raw + (size_t)b * L_DIM;
            #pragma unroll
            for (int i = 0; i < L_DIM / BLK; ++i) {
                const int j = i * BLK + tid;
                unsigned long long bal = __ballot(m[j] != 0.0f);
                if (lane == 0) words[j >> 6] = bal;
            }
        } else {
            const uint8_t* m = mask_raw + (size_t)b * L_DIM;
            #pragma unroll
            for (int i = 0; i < L_DIM / BLK; ++i) {
                const int j = i * BLK + tid;
                unsigned long long bal = __ballot(m[j] != 0);
                if (lane == 0) words[j >> 6] = bal;
            }
        }
    }
    __syncthreads();

    // ---- wave 0: popcount + inclusive shfl-scan over the 64 words
    if (tid < 64) {
        const unsigned long long wd = words[tid];
        const int c = __popcll(wd);
        int inc = c;
        #pragma unroll
        for (int off = 1; off < 64; off <<= 1) {
            int v = __shfl_up(inc, off);
            if (tid >= off) inc += v;
        }
        pref[tid] = inc - c;            // exclusive prefix
        if (tid == 63) nsh = inc;       // n
    }
    __syncthreads();

    // ---- expand bitmask words to pos[] (each thread: one 16-bit chunk)
    {
        const int w      = tid >> 2;
        const int startb = (tid & 3) * 16;
        const unsigned long long wd = words[w];
        const unsigned long long below =
            startb ? (wd & ((1ull << startb) - 1ull)) : 0ull;
        int p = pref[w] + __popcll(below);
        const int base = w * 64 + startb;
        unsigned int chunk = (unsigned int)((wd >> startb) & 0xFFFFull);
        while (chunk) {
            const int bit = __ffs(chunk) - 1;
            pos[p++] = (unsigned short)(base + bit);
            chunk &= chunk - 1;
        }
    }
    __syncthreads();

    const float nf = (float)nsh;
    const float* fb = feats + (size_t)b * L_DIM * D_DIM;

    // ---- gather: each wave owns 2 output rows, interleaved (2 load streams)
    const int t0  = g * ROWS_PER_BLOCK + wv;
    const int t1  = t0 + 4;

    const int s0  = idx_of(t0, nf);
    const int e0  = idx_of(t0 + 1, nf);
    const int lo0 = s0;
    const int hi0 = (e0 > s0) ? e0 : (s0 + 1);
    const int c0  = hi0 - lo0;
    const float inv0 = 1.0f / (float)c0;

    const int s1  = idx_of(t1, nf);
    const int e1  = idx_of(t1 + 1, nf);
    const int lo1 = s1;
    const int hi1 = (e1 > s1) ? e1 : (s1 + 1);
    const int c1  = hi1 - lo1;
    const float inv1 = 1.0f / (float)c1;

    const int cmax = (c0 > c1) ? c0 : c1;

    f32x4 a0 = (f32x4)(0.f);
    f32x4 a1 = (f32x4)(0.f);
    for (int k = 0; k < cmax; ++k) {
        if (k < c0) {                                // wave-uniform branch
            const int r = pos[lo0 + k];              // LDS broadcast
            const f32x4 v = __builtin_nontemporal_load(
                (const f32x4*)(fb + (size_t)r * D_DIM) + lane);
            a0 += v;
        }
        if (k < c1) {
            const int r = pos[lo1 + k];
            const f32x4 v = __builtin_nontemporal_load(
                (const f32x4*)(fb + (size_t)r * D_DIM) + lane);
            a1 += v;
        }
    }
    a0 *= inv0;
    a1 *= inv1;
    __builtin_nontemporal_store(a0, (f32x4*)(out + ((size_t)b * TGT + t0) * D_DIM) + lane);
    __builtin_nontemporal_store(a1, (f32x4*)(out + ((size_t)b * TGT + t1) * D_DIM) + lane);
}

extern "C" void kernel_launch(void* const* d_in, const int* in_sizes, int n_in,
                              void* d_out, int out_size, void* d_ws, size_t ws_size,
                              hipStream_t stream) {
    const float*   feats = (const float*)d_in[0];
    const uint8_t* masks = (const uint8_t*)d_in[1];
    float*         out   = (float*)d_out;
    (void)in_sizes; (void)n_in; (void)out_size; (void)d_ws; (void)ws_size;

    dim3 grid(NG, B_DIM);
    AggregateVideo_kernel<<<grid, BLK, 0, stream>>>(masks, feats, out);
}